// Round 4
// baseline (1148.032 us; speedup 1.0000x reference)
//
#include <hip/hip_runtime.h>
#include <hip/hip_bf16.h>
#include <cstdint>
#include <cstddef>

// Problem constants
#define S_LEN   2048
#define BATCH   2
#define HDIM    4096
#define NHEADS  32
#define NGROUPS 8
#define HEADD   128
#define QKV_N   6144   // HDIM + 2*NGROUPS*HEADD

typedef __attribute__((ext_vector_type(8))) short  short8;   // 8 bf16 = 4 VGPRs
typedef __attribute__((ext_vector_type(4))) float  floatx4;  // MFMA 16x16 accum

__device__ __forceinline__ void async_ld16(const void* g, void* l) {
  __builtin_amdgcn_global_load_lds((const __attribute__((address_space(1))) void*)g,
                                   (__attribute__((address_space(3))) void*)l,
                                   16, 0, 0);
}

// RTNE f32 -> bf16 bits (finite inputs)
__device__ __forceinline__ unsigned short f2bf_bits(float f) {
  unsigned int u = __float_as_uint(f);
  u += 0x7FFFu + ((u >> 16) & 1u);
  return (unsigned short)(u >> 16);
}

// ---------------------------------------------------------------------------
// f32 -> bf16 bulk convert, all three tensors in one launch (fewer gaps)
// ---------------------------------------------------------------------------
__global__ void cvt_all(const float4* __restrict__ x,
                        const float4* __restrict__ wq,
                        const float4* __restrict__ wd,
                        ushort4* __restrict__ xo,
                        ushort4* __restrict__ wqo,
                        ushort4* __restrict__ wdo,
                        int nx, int nq, int nd)
{
  int i = blockIdx.x * blockDim.x + threadIdx.x;
  const float4* src; ushort4* dst; int off;
  if (i < nx)                { src = x;  dst = xo;  off = i; }
  else if (i < nx + nq)      { src = wq; dst = wqo; off = i - nx; }
  else if (i < nx + nq + nd) { src = wd; dst = wdo; off = i - nx - nq; }
  else return;
  const float4 v = src[off];
  ushort4 o;
  o.x = f2bf_bits(v.x); o.y = f2bf_bits(v.y);
  o.z = f2bf_bits(v.z); o.w = f2bf_bits(v.w);
  dst[off] = o;
}

// ---------------------------------------------------------------------------
// GEMM: C[M,N] = A[M,K] @ B[N,K]^T  (bf16, K contiguous), 128x128 tile, BK=64.
// Verified round-0 structure (890 TF): 3 blocks/CU; cross-block wave overlap
// fills the barrier-drain stall. LDS tiles XOR-swizzled at stage time via the
// DMA's global-side gather (conflict-free fragment reads).
// MODE 0: f32 row-major output. MODE 1: QKV scatter epilogue (+bias f32).
// ---------------------------------------------------------------------------
template<int MODE>
__global__ void gemm128(const __hip_bfloat16* __restrict__ A,
                        const __hip_bfloat16* __restrict__ Bm,
                        const float* __restrict__ bias,
                        float* __restrict__ Cout,
                        __hip_bfloat16* __restrict__ Qbuf,
                        __hip_bfloat16* __restrict__ Kbuf,
                        __hip_bfloat16* __restrict__ Vtbuf,
                        int M, int N, int K)
{
  __shared__ short As[128*64];   // 16 KB, 8 chunks(16B) per row
  __shared__ short Bs[128*64];   // 16 KB
  const int mb = blockIdx.y, nb = blockIdx.x;
  const int tid  = threadIdx.x;
  const int wave = tid >> 6, lane = tid & 63;
  const int wm = wave >> 1, wn = wave & 1;
  const int quad = lane >> 4, l15 = lane & 15;

  floatx4 acc[4][4] = {};

  const __hip_bfloat16* Abase = A  + (size_t)mb * 128 * K;
  const __hip_bfloat16* Bbase = Bm + (size_t)nb * 128 * K;

  for (int kb = 0; kb < K; kb += 64) {
    #pragma unroll
    for (int i = 0; i < 4; ++i) {
      const int cb  = (i*4 + wave) * 64;     // wave-uniform chunk base
      const int idx = cb + lane;
      const int r   = idx >> 3, cl = idx & 7;
      const int gc  = cl ^ (r & 7);          // XOR swizzle (global side)
      async_ld16(Abase + (size_t)r*K + kb + gc*8, As + cb*8);
      async_ld16(Bbase + (size_t)r*K + kb + gc*8, Bs + cb*8);
    }
    __syncthreads();

    #pragma unroll
    for (int ks = 0; ks < 2; ++ks) {
      short8 af[4], bf[4];
      #pragma unroll
      for (int mi = 0; mi < 4; ++mi) {
        const int row = wm*64 + mi*16 + l15;
        const int ch  = (ks*4 + quad) ^ (l15 & 7);
        af[mi] = *(const short8*)&As[row*64 + ch*8];
      }
      #pragma unroll
      for (int ni = 0; ni < 4; ++ni) {
        const int row = wn*64 + ni*16 + l15;
        const int ch  = (ks*4 + quad) ^ (l15 & 7);
        bf[ni] = *(const short8*)&Bs[row*64 + ch*8];
      }
      #pragma unroll
      for (int mi = 0; mi < 4; ++mi)
        #pragma unroll
        for (int ni = 0; ni < 4; ++ni)
          acc[mi][ni] = __builtin_amdgcn_mfma_f32_16x16x32_bf16(
              af[mi], bf[ni], acc[mi][ni], 0, 0, 0);
    }
    __syncthreads();
  }

  // epilogue: C/D layout col = lane&15, row = quad*4 + reg
  #pragma unroll
  for (int mi = 0; mi < 4; ++mi) {
    #pragma unroll
    for (int ni = 0; ni < 4; ++ni) {
      const int n = nb*128 + wn*64 + ni*16 + l15;
      float bv = 0.0f;
      if (MODE == 1) bv = bias[n];
      #pragma unroll
      for (int r = 0; r < 4; ++r) {
        const int m = mb*128 + wm*64 + mi*16 + quad*4 + r;
        const float v = acc[mi][ni][r] + bv;
        if (MODE == 0) {
          Cout[(size_t)m*N + n] = v;
        } else {
          const __hip_bfloat16 hv = __float2bfloat16(v);
          const int s  = m >> 1;       // BATCH = 2
          const int bi = m & 1;
          if (n < HDIM) {                     // Q -> (b,h,s,d)
            const int hh = n >> 7, d = n & 127;
            Qbuf[(((size_t)bi*NHEADS + hh)*S_LEN + s)*HEADD + d] = hv;
          } else if (n < HDIM + NGROUPS*HEADD) {  // K -> (b,g,s,d)
            const int gg = (n - HDIM) >> 7, d = n & 127;
            Kbuf[(((size_t)bi*NGROUPS + gg)*S_LEN + s)*HEADD + d] = hv;
          } else {                            // V -> (b,g,d,s) transposed
            const int gg = (n - (HDIM + NGROUPS*HEADD)) >> 7, d = n & 127;
            Vtbuf[(((size_t)bi*NGROUPS + gg)*HEADD + d)*S_LEN + s] = hv;
          }
        }
      }
    }
  }
}

// ---------------------------------------------------------------------------
// RoPE in-place. Q additionally pre-scaled by 1/sqrt(HD)*log2(e) so attention
// scores come out ready for exp2 (no-max softmax). rope_cache: (S,64,2) f32
// ---------------------------------------------------------------------------
__global__ void rope_kernel(__hip_bfloat16* __restrict__ Qbuf,
                            __hip_bfloat16* __restrict__ Kbuf,
                            const float* __restrict__ rope)
{
  const int QP = BATCH*NHEADS*S_LEN*64;
  const int KP = BATCH*NGROUPS*S_LEN*64;
  int idx = blockIdx.x * blockDim.x + threadIdx.x;
  __hip_bfloat16* base;
  int p;
  float post;
  if (idx < QP)            { base = Qbuf; p = idx;      post = 0.12751744061558475f; }
  else if (idx < QP + KP)  { base = Kbuf; p = idx - QP; post = 1.0f; }
  else return;
  const int i    = p & 63;
  const int rest = p >> 6;
  const int s    = rest & (S_LEN - 1);
  const float c  = rope[s*128 + 2*i];
  const float sn = rope[s*128 + 2*i + 1];
  __hip_bfloat16* ptr = base + (size_t)rest*HEADD + 2*i;
  const float x0 = __bfloat162float(ptr[0]);
  const float x1 = __bfloat162float(ptr[1]);
  ptr[0] = __float2bfloat16((x0*c - x1*sn) * post);
  ptr[1] = __float2bfloat16((x1*c + x0*sn) * post);
}

// ---------------------------------------------------------------------------
// Flash attention v6 (round 4): EXACT round-0 (v3) structure — 64 q-rows per
// block, 4 waves x 16 rows, 2048 blocks — with ONE change: V^T is read
// DIRECTLY FROM GLOBAL (L2-resident: 512 KB per (b,g), reused by 64 blocks;
// its (b,g,d,s) layout already gives each lane a contiguous 16B B-fragment).
// This is the guide's verified "don't LDS-stage what L2-fits" pattern (m169).
// Effect: LDS 41->25 KB, pre-barrier DMA halves, occupancy cap moves from
// LDS (12 waves/CU) to VGPR (16 waves/CU) -> +33% latency hiding for the
// serial stage->QK->softmax->PV chain that round-3 counters showed is the
// bottleneck (MfmaUtil 9.7 / VALUBusy 17 / Occ 6.7 = latency-bound).
// __launch_bounds__(256,4) pins <=128 VGPR so bv loads can't hoist+spill.
// ---------------------------------------------------------------------------
__global__ void __launch_bounds__(256, 4)
attn_kernel(const __hip_bfloat16* __restrict__ Qbuf,
            const __hip_bfloat16* __restrict__ Kbuf,
            const __hip_bfloat16* __restrict__ Vtbuf,
            __hip_bfloat16* __restrict__ Obuf)
{
  __shared__ __align__(16) short KtS[64*128];    // 16 KB: [key][d], 16 ch/row
  __shared__ __align__(16) short PtS[4][16*72];  // 9 KB: per-wave P, pad 64->72

  const int qb   = blockIdx.x * 64;
  const int bh   = blockIdx.y;               // b*NHEADS + h
  const int b    = bh >> 5, h = bh & 31;
  const int g    = h >> 2;                   // rep = 4
  const int tid  = threadIdx.x;
  const int wave = tid >> 6, lane = tid & 63;
  const int quad = lane >> 4, l15 = lane & 15;
  const int qw   = qb + wave*16;             // this wave's q rows

  const __hip_bfloat16* Qp = Qbuf  + ((size_t)bh*S_LEN + qw) * HEADD;
  const __hip_bfloat16* Kp = Kbuf  + ((size_t)(b*NGROUPS + g)*S_LEN) * HEADD;
  const __hip_bfloat16* Vp = Vtbuf + ((size_t)(b*NGROUPS + g)*HEADD) * S_LEN;

  // Q fragments (already scaled by 1/sqrt(d)*log2e in rope_kernel)
  short8 aq[4];
  #pragma unroll
  for (int dc = 0; dc < 4; ++dc)
    aq[dc] = *(const short8*)&Qp[(size_t)l15*HEADD + dc*32 + quad*8];

  floatx4 O[8] = {};
  float li[4] = {0.f, 0.f, 0.f, 0.f};   // per-lane partial row sums

  const int ktend = qb + 64;
  for (int kt = 0; kt < ktend; kt += 64) {
    // ---- stage K (64x128) tile only, XOR-swizzled (V is read from L2) ----
    #pragma unroll
    for (int i = 0; i < 4; ++i) {
      const int cb  = (i*4 + wave) * 64;     // wave-uniform chunk base
      const int idx = cb + lane;
      const int r = idx >> 4, cl = idx & 15;
      const int gc = cl ^ (r & 15);          // chunk (r,cl) holds global cl^(r&15)
      async_ld16(Kp + (size_t)(kt + r)*HEADD + gc*8, KtS + cb*8);
    }
    __syncthreads();   // barrier drains vmcnt(0): K tile ready

    // ---- S = Q K^T : 16 rows x 64 keys, 16 MFMAs ----
    floatx4 s[4] = {};
    __builtin_amdgcn_s_setprio(1);
    #pragma unroll
    for (int dc = 0; dc < 4; ++dc) {
      #pragma unroll
      for (int kc = 0; kc < 4; ++kc) {
        const int row = kc*16 + l15;
        const int ch  = (dc*4 + quad) ^ l15;
        const short8 bk = *(const short8*)&KtS[row*128 + ch*8];
        s[kc] = __builtin_amdgcn_mfma_f32_16x16x32_bf16(aq[dc], bk, s[kc], 0, 0, 0);
      }
    }
    __builtin_amdgcn_s_setprio(0);

    // ---- no-max softmax: p = exp2(s); mask only on diagonal iteration ----
    if (kt == qb) {
      #pragma unroll
      for (int r = 0; r < 4; ++r) {
        const int row = qw + quad*4 + r;
        float rs = 0.f;
        #pragma unroll
        for (int kc = 0; kc < 4; ++kc) {
          const int col = kt + kc*16 + l15;
          const float p = (col > row) ? 0.0f : __builtin_amdgcn_exp2f(s[kc][r]);
          s[kc][r] = p; rs += p;
        }
        li[r] += rs;
      }
    } else {
      #pragma unroll
      for (int r = 0; r < 4; ++r) {
        float rs = 0.f;
        #pragma unroll
        for (int kc = 0; kc < 4; ++kc) {
          const float p = __builtin_amdgcn_exp2f(s[kc][r]);
          s[kc][r] = p; rs += p;
        }
        li[r] += rs;
      }
    }

    // ---- P: C-layout -> A-layout via wave-private padded LDS tile ----
    #pragma unroll
    for (int r = 0; r < 4; ++r)
      #pragma unroll
      for (int kc = 0; kc < 4; ++kc)
        PtS[wave][(quad*4 + r)*72 + kc*16 + l15] = (short)f2bf_bits(s[kc][r]);
    // same-wave RAW through LDS: ordered by lgkmcnt, no block barrier needed
    const short8 pa0 = *(const short8*)&PtS[wave][l15*72 +      quad*8];
    const short8 pa1 = *(const short8*)&PtS[wave][l15*72 + 32 + quad*8];

    // ---- O += P V : 16 MFMAs; V^T fragments straight from global (L2) ----
    __builtin_amdgcn_s_setprio(1);
    #pragma unroll
    for (int dt = 0; dt < 8; ++dt) {
      const int row = dt*16 + l15;
      const short8 bv0 = *(const short8*)&Vp[(size_t)row*S_LEN + kt      + quad*8];
      const short8 bv1 = *(const short8*)&Vp[(size_t)row*S_LEN + kt + 32 + quad*8];
      O[dt] = __builtin_amdgcn_mfma_f32_16x16x32_bf16(pa0, bv0, O[dt], 0, 0, 0);
      O[dt] = __builtin_amdgcn_mfma_f32_16x16x32_bf16(pa1, bv1, O[dt], 0, 0, 0);
    }
    __builtin_amdgcn_s_setprio(0);

    __syncthreads();   // all K-tile reads done before next stage overwrites
  }

  // ---- epilogue: reduce l across the 16 col-lanes, scale, write ----
  float inv[4];
  #pragma unroll
  for (int r = 0; r < 4; ++r) {
    float l = li[r];
    l += __shfl_xor(l, 1, 16);
    l += __shfl_xor(l, 2, 16);
    l += __shfl_xor(l, 4, 16);
    l += __shfl_xor(l, 8, 16);
    inv[r] = 1.0f / l;
  }
  #pragma unroll
  for (int dt = 0; dt < 8; ++dt)
    #pragma unroll
    for (int r = 0; r < 4; ++r) {
      const int row = qw + quad*4 + r;
      Obuf[((size_t)row*BATCH + b)*HDIM + h*HEADD + dt*16 + l15] =
          __float2bfloat16(O[dt][r] * inv[r]);
    }
}

// ---------------------------------------------------------------------------
extern "C" void kernel_launch(void* const* d_in, const int* in_sizes, int n_in,
                              void* d_out, int out_size, void* d_ws, size_t ws_size,
                              hipStream_t stream)
{
  const float* x    = (const float*)d_in[0];
  const float* rope = (const float*)d_in[1];
  const float* Wqkv = (const float*)d_in[2];
  const float* bqkv = (const float*)d_in[3];
  const float* Wd   = (const float*)d_in[4];
  float* out = (float*)d_out;

  const size_t MiB = 1024*1024;
  char* ws = (char*)d_ws;
  __hip_bfloat16* xb    = (__hip_bfloat16*)(ws);              // 32 MiB
  __hip_bfloat16* Wqkvb = (__hip_bfloat16*)(ws + 32*MiB);     // 48 MiB
  __hip_bfloat16* Wdb   = (__hip_bfloat16*)(ws + 80*MiB);     // 32 MiB
  __hip_bfloat16* Qbuf  = (__hip_bfloat16*)(ws + 112*MiB);    // 32 MiB
  __hip_bfloat16* Kbuf  = (__hip_bfloat16*)(ws + 144*MiB);    //  8 MiB
  __hip_bfloat16* Vt    = (__hip_bfloat16*)(ws + 152*MiB);    //  8 MiB
  __hip_bfloat16* Ob    = (__hip_bfloat16*)(ws + 160*MiB);    // 32 MiB

  // 0) f32 -> bf16 conversions (single fused launch)
  {
    const int nx = S_LEN*BATCH*HDIM/4;
    const int nq = QKV_N*HDIM/4;
    const int nd = HDIM*HDIM/4;
    const int nt = nx + nq + nd;
    cvt_all<<<(nt+255)/256, 256, 0, stream>>>(
        (const float4*)x, (const float4*)Wqkv, (const float4*)Wd,
        (ushort4*)xb, (ushort4*)Wqkvb, (ushort4*)Wdb, nx, nq, nd);
  }

  // 1) QKV projection + scatter (M=4096, N=6144, K=4096)
  dim3 g1(QKV_N/128, (S_LEN*BATCH)/128);
  gemm128<1><<<g1, 256, 0, stream>>>(xb, Wqkvb, bqkv, nullptr,
                                     Qbuf, Kbuf, Vt,
                                     S_LEN*BATCH, QKV_N, HDIM);

  // 2) RoPE in-place on Q (+softmax prescale) and K
  const int total_pairs = BATCH*(NHEADS+NGROUPS)*S_LEN*64;
  rope_kernel<<<total_pairs/256, 256, 0, stream>>>(Qbuf, Kbuf, rope);

  // 3) causal flash attention (64 q-rows per block, 4 waves)
  dim3 ga(S_LEN/64, BATCH*NHEADS);
  attn_kernel<<<ga, 256, 0, stream>>>(Qbuf, Kbuf, Vt, Ob);

  // 4) dense projection (M=4096, N=4096, K=4096), f32 out
  dim3 g2(HDIM/128, (S_LEN*BATCH)/128);
  gemm128<0><<<g2, 256, 0, stream>>>(Ob, Wdb, nullptr, out,
                                     nullptr, nullptr, nullptr,
                                     S_LEN*BATCH, HDIM, HDIM);
}

// Round 6
// 888.460 us; speedup vs baseline: 1.2922x; 1.2922x over previous
//
#include <hip/hip_runtime.h>
#include <hip/hip_bf16.h>
#include <cstdint>
#include <cstddef>

// Problem constants
#define S_LEN   2048
#define BATCH   2
#define HDIM    4096
#define NHEADS  32
#define NGROUPS 8
#define HEADD   128
#define QKV_N   6144   // HDIM + 2*NGROUPS*HEADD

typedef __attribute__((ext_vector_type(8))) short  short8;   // 8 bf16 = 4 VGPRs
typedef __attribute__((ext_vector_type(4))) float  floatx4;  // MFMA 16x16 accum

__device__ __forceinline__ void async_ld16(const void* g, void* l) {
  __builtin_amdgcn_global_load_lds((const __attribute__((address_space(1))) void*)g,
                                   (__attribute__((address_space(3))) void*)l,
                                   16, 0, 0);
}

// RTNE f32 -> bf16 bits (finite inputs)
__device__ __forceinline__ unsigned short f2bf_bits(float f) {
  unsigned int u = __float_as_uint(f);
  u += 0x7FFFu + ((u >> 16) & 1u);
  return (unsigned short)(u >> 16);
}

// ---------------------------------------------------------------------------
// f32 -> bf16 bulk convert, all three tensors in one launch
// ---------------------------------------------------------------------------
__global__ void cvt_all(const float4* __restrict__ x,
                        const float4* __restrict__ wq,
                        const float4* __restrict__ wd,
                        ushort4* __restrict__ xo,
                        ushort4* __restrict__ wqo,
                        ushort4* __restrict__ wdo,
                        int nx, int nq, int nd)
{
  int i = blockIdx.x * blockDim.x + threadIdx.x;
  const float4* src; ushort4* dst; int off;
  if (i < nx)                { src = x;  dst = xo;  off = i; }
  else if (i < nx + nq)      { src = wq; dst = wqo; off = i - nx; }
  else if (i < nx + nq + nd) { src = wd; dst = wdo; off = i - nx - nq; }
  else return;
  const float4 v = src[off];
  ushort4 o;
  o.x = f2bf_bits(v.x); o.y = f2bf_bits(v.y);
  o.z = f2bf_bits(v.z); o.w = f2bf_bits(v.w);
  dst[off] = o;
}

// ---------------------------------------------------------------------------
// GEMM round-6: 256x256 tile, BK=64, 8 waves (2M x 4N), 8-phase schedule.
// ROUND-5 BUG FIXED: stages are now split at the row-64 boundary (the j_=0/1
// load split), matching the phase split of the ds_reads:
//   A rows 0-63  read ph1 -> SA_LO staged ph2 (buf0) / ph6 (buf1)
//   B (all rows) read ph1-2 -> SB_LO+SB_HI staged ph3 / ph7
//   A rows 64-127 read ph3 -> SA_HI staged ph4 / ph8
// Every stage is issued AFTER the closing barrier of its region's last-read
// phase (all waves' lgkmcnt(0) precede that barrier), so the DMA can never
// overwrite not-yet-read data.
// Gates (verified FIFO arithmetic, 16 loads/iter in flight):
//   end-ph4 GATE(8): drains prev ph6/7/8 = buf1's 8 loads (read ph5-8);
//   end-ph8 GATE(8): drains ph2/3/4 = buf0-next's 8 loads (read ph1'-4').
// Minimum stage->gate distance = 4 phases (~600-800 cy of MFMA+barrier work).
// Prologue stages buf0 then buf1 (8+8 loads) + GATE(8): iter 0 = steady state.
// MODE 0: f32 row-major output. MODE 1: QKV scatter epilogue (+bias f32).
// ---------------------------------------------------------------------------
template<int MODE>
__global__ void __launch_bounds__(512, 2)
gemm256(const __hip_bfloat16* __restrict__ A,
        const __hip_bfloat16* __restrict__ Bm,
        const float* __restrict__ bias,
        float* __restrict__ Cout,
        __hip_bfloat16* __restrict__ Qbuf,
        __hip_bfloat16* __restrict__ Kbuf,
        __hip_bfloat16* __restrict__ Vtbuf,
        int M, int N, int K)
{
  __shared__ __align__(16) short As[2][2][128*64];   // [buf][half] 64 KiB
  __shared__ __align__(16) short Bs[2][2][128*64];   // 64 KiB

  // bijective XCD swizzle (both grids are multiples of 8 blocks)
  const int nbx = N >> 8;
  const int nwg = (M >> 8) * nbx;
  int bid = blockIdx.x;
  { const int cpx = nwg >> 3; bid = (bid & 7) * cpx + (bid >> 3); }
  const int mb = bid / nbx, nb = bid - mb * nbx;

  const int tid  = threadIdx.x;
  const int wave = tid >> 6, lane = tid & 63;
  const int wm = wave >> 2, wn = wave & 3;        // 2M x 4N wave grid
  const int quad = lane >> 4, l15 = lane & 15;

  const __hip_bfloat16* Abase = A  + (size_t)mb * 256 * K;
  const __hip_bfloat16* Bbase = Bm + (size_t)nb * 256 * K;

  floatx4 acc[8][4] = {};      // wave tile 128x64
  short8  afr[4][2];           // A frags (one mh quad), [mi][ks]
  short8  bfr[4][2];           // B frags (all 4 ni),    [ni][ks]

#define BARRIER() do { __builtin_amdgcn_s_barrier(); \
                       asm volatile("" ::: "memory"); } while (0)
#define GATE(n)   asm volatile("s_waitcnt vmcnt(" #n ")" ::: "memory")

// stage rows 0-63 of both A halves (2 loads)
#define SA_LO(buf, kb) do { \
    _Pragma("unroll") \
    for (int h_ = 0; h_ < 2; ++h_) { \
      const int cb_  = wave*64; \
      const int idx_ = cb_ + lane; \
      const int r_ = idx_ >> 3, gc_ = (idx_ & 7) ^ (r_ & 7); \
      async_ld16(Abase + (size_t)(h_*128 + r_)*K + (kb) + gc_*8, \
                 &As[buf][h_][cb_*8]); \
    } } while (0)

// stage rows 64-127 of both A halves (2 loads)
#define SA_HI(buf, kb) do { \
    _Pragma("unroll") \
    for (int h_ = 0; h_ < 2; ++h_) { \
      const int cb_  = 512 + wave*64; \
      const int idx_ = cb_ + lane; \
      const int r_ = idx_ >> 3, gc_ = (idx_ & 7) ^ (r_ & 7); \
      async_ld16(Abase + (size_t)(h_*128 + r_)*K + (kb) + gc_*8, \
                 &As[buf][h_][cb_*8]); \
    } } while (0)

#define SB_LO(buf, kb) do { \
    _Pragma("unroll") \
    for (int h_ = 0; h_ < 2; ++h_) { \
      const int cb_  = wave*64; \
      const int idx_ = cb_ + lane; \
      const int r_ = idx_ >> 3, gc_ = (idx_ & 7) ^ (r_ & 7); \
      async_ld16(Bbase + (size_t)(h_*128 + r_)*K + (kb) + gc_*8, \
                 &Bs[buf][h_][cb_*8]); \
    } } while (0)

#define SB_HI(buf, kb) do { \
    _Pragma("unroll") \
    for (int h_ = 0; h_ < 2; ++h_) { \
      const int cb_  = 512 + wave*64; \
      const int idx_ = cb_ + lane; \
      const int r_ = idx_ >> 3, gc_ = (idx_ & 7) ^ (r_ & 7); \
      async_ld16(Bbase + (size_t)(h_*128 + r_)*K + (kb) + gc_*8, \
                 &Bs[buf][h_][cb_*8]); \
    } } while (0)

#define LDA4(buf, mh) do { \
    _Pragma("unroll") \
    for (int mi_ = 0; mi_ < 4; ++mi_) { \
      const short* b_ = &As[buf][wm][(((mh)*4 + mi_)*16 + l15)*64]; \
      _Pragma("unroll") \
      for (int ks_ = 0; ks_ < 2; ++ks_) \
        afr[mi_][ks_] = *(const short8*)&b_[((ks_*4 + quad) ^ (l15 & 7))*8]; \
    } } while (0)

#define LDB2(buf, nh) do { \
    _Pragma("unroll") \
    for (int ni_ = 0; ni_ < 2; ++ni_) { \
      const short* b_ = &Bs[buf][wn >> 1][((wn & 1)*64 + ((nh)*2 + ni_)*16 + l15)*64]; \
      _Pragma("unroll") \
      for (int ks_ = 0; ks_ < 2; ++ks_) \
        bfr[(nh)*2 + ni_][ks_] = *(const short8*)&b_[((ks_*4 + quad) ^ (l15 & 7))*8]; \
    } } while (0)

#define MFMA16(mh, nh) do { \
    asm volatile("s_waitcnt lgkmcnt(0)" ::: "memory"); \
    __builtin_amdgcn_s_setprio(1); \
    _Pragma("unroll") \
    for (int mi_ = 0; mi_ < 4; ++mi_) \
      _Pragma("unroll") \
      for (int ni_ = 0; ni_ < 2; ++ni_) \
        _Pragma("unroll") \
        for (int ks_ = 0; ks_ < 2; ++ks_) \
          acc[(mh)*4 + mi_][(nh)*2 + ni_] = \
              __builtin_amdgcn_mfma_f32_16x16x32_bf16( \
                  afr[mi_][ks_], bfr[(nh)*2 + ni_][ks_], \
                  acc[(mh)*4 + mi_][(nh)*2 + ni_], 0, 0, 0); \
    __builtin_amdgcn_s_setprio(0); \
  } while (0)

  // ---- prologue: tile0 -> buf0 (8 loads), tile1 -> buf1 (8 loads) ----
  SA_LO(0, 0);  SA_HI(0, 0);  SB_LO(0, 0);  SB_HI(0, 0);
  SA_LO(1, 64); SA_HI(1, 64); SB_LO(1, 64); SB_HI(1, 64);
  GATE(8);                         // buf0 landed; buf1's 8 loads in flight
  BARRIER();

  const int NI = K >> 7;           // 2 K-tiles per iteration
  for (int i = 0; i < NI; ++i) {
    int kb2 = (i << 7) + 128; if (kb2 > K - 64) kb2 = K - 64;  // tile 2i+2
    int kb3 = (i << 7) + 192; if (kb3 > K - 64) kb3 = K - 64;  // tile 2i+3

    // ph1: quad (0,0) of buf0 (reads A rows 0-63, B lo-rows)
    LDA4(0, 0); LDB2(0, 0);
    asm volatile("s_waitcnt lgkmcnt(8)" ::: "memory");
    BARRIER(); MFMA16(0, 0); BARRIER();
    // ph2: (0,1) (reads B hi-rows); stage A rows 0-63 (buf0 <- tile 2i+2)
    LDB2(0, 1);
    SA_LO(0, kb2);
    BARRIER(); MFMA16(0, 1); BARRIER();
    // ph3: (1,1) (reads A rows 64-127); stage all B (buf0)
    LDA4(0, 1);
    SB_LO(0, kb2); SB_HI(0, kb2);
    BARRIER(); MFMA16(1, 1); BARRIER();
    // ph4: (1,0) (register-only); stage A rows 64-127 (buf0); gate buf1
    SA_HI(0, kb2);
    BARRIER(); MFMA16(1, 0);
    GATE(8);                       // drains prev ph6/7/8: buf1 tile landed
    BARRIER();
    // ph5: quad (0,0) of buf1
    LDA4(1, 0); LDB2(1, 0);
    asm volatile("s_waitcnt lgkmcnt(8)" ::: "memory");
    BARRIER(); MFMA16(0, 0); BARRIER();
    // ph6: (0,1); stage A rows 0-63 (buf1 <- tile 2i+3)
    LDB2(1, 1);
    SA_LO(1, kb3);
    BARRIER(); MFMA16(0, 1); BARRIER();
    // ph7: (1,1); stage all B (buf1)
    LDA4(1, 1);
    SB_LO(1, kb3); SB_HI(1, kb3);
    BARRIER(); MFMA16(1, 1); BARRIER();
    // ph8: (1,0); stage A rows 64-127 (buf1); gate buf0-next
    SA_HI(1, kb3);
    BARRIER(); MFMA16(1, 0);
    GATE(8);                       // drains ph2/3/4: buf0 next tile landed
    BARRIER();
  }
  GATE(0);                         // drain stale stages before LDS dealloc

#undef BARRIER
#undef GATE
#undef SA_LO
#undef SA_HI
#undef SB_LO
#undef SB_HI
#undef LDA4
#undef LDB2
#undef MFMA16

  // epilogue: C/D layout col = lane&15, row = quad*4 + reg
  #pragma unroll
  for (int mi = 0; mi < 8; ++mi) {
    #pragma unroll
    for (int ni = 0; ni < 4; ++ni) {
      const int n = nb*256 + wn*64 + ni*16 + l15;
      float bv = 0.0f;
      if (MODE == 1) bv = bias[n];
      #pragma unroll
      for (int r = 0; r < 4; ++r) {
        const int m = mb*256 + wm*128 + mi*16 + quad*4 + r;
        const float v = acc[mi][ni][r] + bv;
        if (MODE == 0) {
          Cout[(size_t)m*N + n] = v;
        } else {
          const __hip_bfloat16 hv = __float2bfloat16(v);
          const int s  = m >> 1;       // BATCH = 2
          const int bi = m & 1;
          if (n < HDIM) {                     // Q -> (b,h,s,d)
            const int hh = n >> 7, d = n & 127;
            Qbuf[(((size_t)bi*NHEADS + hh)*S_LEN + s)*HEADD + d] = hv;
          } else if (n < HDIM + NGROUPS*HEADD) {  // K -> (b,g,s,d)
            const int gg = (n - HDIM) >> 7, d = n & 127;
            Kbuf[(((size_t)bi*NGROUPS + gg)*S_LEN + s)*HEADD + d] = hv;
          } else {                            // V -> (b,g,d,s) transposed
            const int gg = (n - (HDIM + NGROUPS*HEADD)) >> 7, d = n & 127;
            Vtbuf[(((size_t)bi*NGROUPS + gg)*HEADD + d)*S_LEN + s] = hv;
          }
        }
      }
    }
  }
}

// ---------------------------------------------------------------------------
// RoPE in-place. Q additionally pre-scaled by 1/sqrt(HD)*log2(e) so attention
// scores come out ready for exp2 (no-max softmax). rope_cache: (S,64,2) f32
// ---------------------------------------------------------------------------
__global__ void rope_kernel(__hip_bfloat16* __restrict__ Qbuf,
                            __hip_bfloat16* __restrict__ Kbuf,
                            const float* __restrict__ rope)
{
  const int QP = BATCH*NHEADS*S_LEN*64;
  const int KP = BATCH*NGROUPS*S_LEN*64;
  int idx = blockIdx.x * blockDim.x + threadIdx.x;
  __hip_bfloat16* base;
  int p;
  float post;
  if (idx < QP)            { base = Qbuf; p = idx;      post = 0.12751744061558475f; }
  else if (idx < QP + KP)  { base = Kbuf; p = idx - QP; post = 1.0f; }
  else return;
  const int i    = p & 63;
  const int rest = p >> 6;
  const int s    = rest & (S_LEN - 1);
  const float c  = rope[s*128 + 2*i];
  const float sn = rope[s*128 + 2*i + 1];
  __hip_bfloat16* ptr = base + (size_t)rest*HEADD + 2*i;
  const float x0 = __bfloat162float(ptr[0]);
  const float x1 = __bfloat162float(ptr[1]);
  ptr[0] = __float2bfloat16((x0*c - x1*sn) * post);
  ptr[1] = __float2bfloat16((x1*c + x0*sn) * post);
}

// ---------------------------------------------------------------------------
// Flash attention v3 (verified 164 us): causal, GQA rep=4.
// Block = 4 waves x 16 q-rows; K/V tiles (64 keys) staged via XOR-swizzled
// DMA (conflict-free fragment reads). No-max softmax. Mask only on the
// diagonal iteration. 2 barriers/iter; 12 waves/CU of cross-block overlap
// hides the serial chain (rounds 1/2/4 proved: do not change this structure).
// ---------------------------------------------------------------------------
__global__ void __launch_bounds__(256)
attn_kernel(const __hip_bfloat16* __restrict__ Qbuf,
            const __hip_bfloat16* __restrict__ Kbuf,
            const __hip_bfloat16* __restrict__ Vtbuf,
            __hip_bfloat16* __restrict__ Obuf)
{
  __shared__ __align__(16) short KtS[64*128];    // 16 KB: [key][d], 16 ch/row
  __shared__ __align__(16) short VtS[128*64];    // 16 KB: [d][key], 8 ch/row
  __shared__ __align__(16) short PtS[4][16*72];  // 9 KB: per-wave P, pad 64->72

  const int qb   = blockIdx.x * 64;
  const int bh   = blockIdx.y;               // b*NHEADS + h
  const int b    = bh >> 5, h = bh & 31;
  const int g    = h >> 2;                   // rep = 4
  const int tid  = threadIdx.x;
  const int wave = tid >> 6, lane = tid & 63;
  const int quad = lane >> 4, l15 = lane & 15;
  const int qw   = qb + wave*16;             // this wave's q rows

  const __hip_bfloat16* Qp = Qbuf  + ((size_t)bh*S_LEN + qw) * HEADD;
  const __hip_bfloat16* Kp = Kbuf  + ((size_t)(b*NGROUPS + g)*S_LEN) * HEADD;
  const __hip_bfloat16* Vp = Vtbuf + ((size_t)(b*NGROUPS + g)*HEADD) * S_LEN;

  // Q fragments (already scaled by 1/sqrt(d)*log2e in rope_kernel)
  short8 aq[4];
  #pragma unroll
  for (int dc = 0; dc < 4; ++dc)
    aq[dc] = *(const short8*)&Qp[(size_t)l15*HEADD + dc*32 + quad*8];

  floatx4 O[8] = {};
  float li[4] = {0.f, 0.f, 0.f, 0.f};   // per-lane partial row sums

  const int ktend = qb + 64;
  for (int kt = 0; kt < ktend; kt += 64) {
    // ---- stage K (64x128) and V^T (128x64) tiles, XOR-swizzled ----
    #pragma unroll
    for (int i = 0; i < 4; ++i) {
      const int cb  = (i*4 + wave) * 64;     // wave-uniform chunk base
      const int idx = cb + lane;
      { // K: 16 chunks per key row; chunk (r,cl) holds global chunk cl^(r&15)
        const int r = idx >> 4, cl = idx & 15;
        const int gc = cl ^ (r & 15);
        async_ld16(Kp + (size_t)(kt + r)*HEADD + gc*8, KtS + cb*8);
      }
      { // V: 8 chunks per d row; chunk (r,cl) holds global chunk cl^(r&7)
        const int r = idx >> 3, cl = idx & 7;
        const int gc = cl ^ (r & 7);
        async_ld16(Vp + (size_t)r*S_LEN + kt + gc*8, VtS + cb*8);
      }
    }
    __syncthreads();   // barrier drains vmcnt(0): tiles ready

    // ---- S = Q K^T : 16 rows x 64 keys, 16 MFMAs ----
    floatx4 s[4] = {};
    __builtin_amdgcn_s_setprio(1);
    #pragma unroll
    for (int dc = 0; dc < 4; ++dc) {
      #pragma unroll
      for (int kc = 0; kc < 4; ++kc) {
        const int row = kc*16 + l15;
        const int ch  = (dc*4 + quad) ^ l15;
        const short8 bk = *(const short8*)&KtS[row*128 + ch*8];
        s[kc] = __builtin_amdgcn_mfma_f32_16x16x32_bf16(aq[dc], bk, s[kc], 0, 0, 0);
      }
    }
    __builtin_amdgcn_s_setprio(0);

    // ---- no-max softmax: p = exp2(s); mask only on diagonal iteration ----
    if (kt == qb) {
      #pragma unroll
      for (int r = 0; r < 4; ++r) {
        const int row = qw + quad*4 + r;
        float rs = 0.f;
        #pragma unroll
        for (int kc = 0; kc < 4; ++kc) {
          const int col = kt + kc*16 + l15;
          const float p = (col > row) ? 0.0f : __builtin_amdgcn_exp2f(s[kc][r]);
          s[kc][r] = p; rs += p;
        }
        li[r] += rs;
      }
    } else {
      #pragma unroll
      for (int r = 0; r < 4; ++r) {
        float rs = 0.f;
        #pragma unroll
        for (int kc = 0; kc < 4; ++kc) {
          const float p = __builtin_amdgcn_exp2f(s[kc][r]);
          s[kc][r] = p; rs += p;
        }
        li[r] += rs;
      }
    }

    // ---- P: C-layout -> A-layout via wave-private padded LDS tile ----
    #pragma unroll
    for (int r = 0; r < 4; ++r)
      #pragma unroll
      for (int kc = 0; kc < 4; ++kc)
        PtS[wave][(quad*4 + r)*72 + kc*16 + l15] = (short)f2bf_bits(s[kc][r]);
    // same-wave RAW through LDS: ordered by lgkmcnt, no block barrier needed
    const short8 pa0 = *(const short8*)&PtS[wave][l15*72 +      quad*8];
    const short8 pa1 = *(const short8*)&PtS[wave][l15*72 + 32 + quad*8];

    // ---- O += P V : 16 MFMAs ----
    __builtin_amdgcn_s_setprio(1);
    #pragma unroll
    for (int dt = 0; dt < 8; ++dt) {
      const int row = dt*16 + l15;
      const int c0 = quad ^ (l15 & 7);
      const int c1 = (4 + quad) ^ (l15 & 7);
      const short8 bv0 = *(const short8*)&VtS[row*64 + c0*8];
      const short8 bv1 = *(const short8*)&VtS[row*64 + c1*8];
      O[dt] = __builtin_amdgcn_mfma_f32_16x16x32_bf16(pa0, bv0, O[dt], 0, 0, 0);
      O[dt] = __builtin_amdgcn_mfma_f32_16x16x32_bf16(pa1, bv1, O[dt], 0, 0, 0);
    }
    __builtin_amdgcn_s_setprio(0);

    __syncthreads();   // all tile reads done before next stage overwrites
  }

  // ---- epilogue: reduce l across the 16 col-lanes, scale, write ----
  float inv[4];
  #pragma unroll
  for (int r = 0; r < 4; ++r) {
    float l = li[r];
    l += __shfl_xor(l, 1, 16);
    l += __shfl_xor(l, 2, 16);
    l += __shfl_xor(l, 4, 16);
    l += __shfl_xor(l, 8, 16);
    inv[r] = 1.0f / l;
  }
  #pragma unroll
  for (int dt = 0; dt < 8; ++dt)
    #pragma unroll
    for (int r = 0; r < 4; ++r) {
      const int row = qw + quad*4 + r;
      Obuf[((size_t)row*BATCH + b)*HDIM + h*HEADD + dt*16 + l15] =
          __float2bfloat16(O[dt][r] * inv[r]);
    }
}

// ---------------------------------------------------------------------------
extern "C" void kernel_launch(void* const* d_in, const int* in_sizes, int n_in,
                              void* d_out, int out_size, void* d_ws, size_t ws_size,
                              hipStream_t stream)
{
  const float* x    = (const float*)d_in[0];
  const float* rope = (const float*)d_in[1];
  const float* Wqkv = (const float*)d_in[2];
  const float* bqkv = (const float*)d_in[3];
  const float* Wd   = (const float*)d_in[4];
  float* out = (float*)d_out;

  const size_t MiB = 1024*1024;
  char* ws = (char*)d_ws;
  __hip_bfloat16* xb    = (__hip_bfloat16*)(ws);              // 32 MiB
  __hip_bfloat16* Wqkvb = (__hip_bfloat16*)(ws + 32*MiB);     // 48 MiB
  __hip_bfloat16* Wdb   = (__hip_bfloat16*)(ws + 80*MiB);     // 32 MiB
  __hip_bfloat16* Qbuf  = (__hip_bfloat16*)(ws + 112*MiB);    // 32 MiB
  __hip_bfloat16* Kbuf  = (__hip_bfloat16*)(ws + 144*MiB);    //  8 MiB
  __hip_bfloat16* Vt    = (__hip_bfloat16*)(ws + 152*MiB);    //  8 MiB
  __hip_bfloat16* Ob    = (__hip_bfloat16*)(ws + 160*MiB);    // 32 MiB

  // 0) f32 -> bf16 conversions (single fused launch)
  {
    const int nx = S_LEN*BATCH*HDIM/4;
    const int nq = QKV_N*HDIM/4;
    const int nd = HDIM*HDIM/4;
    const int nt = nx + nq + nd;
    cvt_all<<<(nt+255)/256, 256, 0, stream>>>(
        (const float4*)x, (const float4*)Wqkv, (const float4*)Wd,
        (ushort4*)xb, (ushort4*)Wqkvb, (ushort4*)Wdb, nx, nq, nd);
  }

  // 1) QKV projection + scatter (M=4096, N=6144, K=4096), 24x16=384 blocks
  gemm256<1><<<dim3((QKV_N/256)*((S_LEN*BATCH)/256)), dim3(512), 0, stream>>>(
      xb, Wqkvb, bqkv, nullptr, Qbuf, Kbuf, Vt, S_LEN*BATCH, QKV_N, HDIM);

  // 2) RoPE in-place on Q (+softmax prescale) and K
  const int total_pairs = BATCH*(NHEADS+NGROUPS)*S_LEN*64;
  rope_kernel<<<total_pairs/256, 256, 0, stream>>>(Qbuf, Kbuf, rope);

  // 3) causal flash attention (64 q-rows per block, 4 waves)
  dim3 ga(S_LEN/64, BATCH*NHEADS);
  attn_kernel<<<ga, 256, 0, stream>>>(Qbuf, Kbuf, Vt, Ob);

  // 4) dense projection (M=4096, N=4096, K=4096), 16x16=256 blocks, f32 out
  gemm256<0><<<dim3((HDIM/256)*((S_LEN*BATCH)/256)), dim3(512), 0, stream>>>(
      Ob, Wdb, nullptr, out, nullptr, nullptr, nullptr, S_LEN*BATCH, HDIM, HDIM);
}

// Round 7
// 807.466 us; speedup vs baseline: 1.4218x; 1.1003x over previous
//
#include <hip/hip_runtime.h>
#include <hip/hip_bf16.h>
#include <cstdint>
#include <cstddef>

// Problem constants
#define S_LEN   2048
#define BATCH   2
#define HDIM    4096
#define NHEADS  32
#define NGROUPS 8
#define HEADD   128
#define QKV_N   6144   // HDIM + 2*NGROUPS*HEADD

typedef __attribute__((ext_vector_type(8))) short  short8;   // 8 bf16 = 4 VGPRs
typedef __attribute__((ext_vector_type(4))) float  floatx4;  // MFMA 16x16 accum

__device__ __forceinline__ void async_ld16(const void* g, void* l) {
  __builtin_amdgcn_global_load_lds((const __attribute__((address_space(1))) void*)g,
                                   (__attribute__((address_space(3))) void*)l,
                                   16, 0, 0);
}

// RTNE f32 -> bf16 bits (finite inputs)
__device__ __forceinline__ unsigned short f2bf_bits(float f) {
  unsigned int u = __float_as_uint(f);
  u += 0x7FFFu + ((u >> 16) & 1u);
  return (unsigned short)(u >> 16);
}

// ---------------------------------------------------------------------------
// f32 -> bf16 bulk convert, all three tensors in one launch
// ---------------------------------------------------------------------------
__global__ void cvt_all(const float4* __restrict__ x,
                        const float4* __restrict__ wq,
                        const float4* __restrict__ wd,
                        ushort4* __restrict__ xo,
                        ushort4* __restrict__ wqo,
                        ushort4* __restrict__ wdo,
                        int nx, int nq, int nd)
{
  int i = blockIdx.x * blockDim.x + threadIdx.x;
  const float4* src; ushort4* dst; int off;
  if (i < nx)                { src = x;  dst = xo;  off = i; }
  else if (i < nx + nq)      { src = wq; dst = wqo; off = i - nx; }
  else if (i < nx + nq + nd) { src = wd; dst = wdo; off = i - nx - nq; }
  else return;
  const float4 v = src[off];
  ushort4 o;
  o.x = f2bf_bits(v.x); o.y = f2bf_bits(v.y);
  o.z = f2bf_bits(v.z); o.w = f2bf_bits(v.w);
  dst[off] = o;
}

// ---------------------------------------------------------------------------
// GEMM: C[M,N] = A[M,K] @ B[N,K]^T  (bf16, K contiguous), 128x128 tile, BK=64.
// Verified round-0 structure (890 TF, 3 blocks/CU; cross-block wave overlap
// fills the barrier-drain stall). [round-7: the 256^2 8-phase was retired —
// two independent schedules both landed at 329 us / MfmaUtil 26%: at
// 1 block/CU its 16 lockstep barriers/iter have no cross-block overlap to
// hide them. Structural, not fixable by stagger.]
// LDS tiles XOR-swizzled at stage time via the DMA's global-side gather.
// MODE 0: f32 row-major output.
// MODE 1: QKV scatter epilogue (+bias) with FUSED RoPE (round-7): the rotate
//   partner of output n is n^1, held by lane^1 (same row), so
//   vp = shfl_xor(v,1); o = v*cos +/- vp*sin (sign = d&1). Matches
//   the old rope_kernel algebra exactly; Q additionally pre-scaled by
//   1/sqrt(128)*log2e for the exp2-domain no-max softmax. One fewer bf16
//   rounding than the separate rope pass.
// __launch_bounds__(256,4): arch VGPR 60 (+64 acc) fits 4 waves/EU; if the
// prior ~3 blocks/CU residency was a compiler target artifact, dense's
// 1024-block grid becomes exactly 4 blocks/CU (no 1.33-round tail).
// ---------------------------------------------------------------------------
template<int MODE>
__global__ void __launch_bounds__(256, 4)
gemm128(const __hip_bfloat16* __restrict__ A,
        const __hip_bfloat16* __restrict__ Bm,
        const float* __restrict__ bias,
        const float* __restrict__ rope,
        float* __restrict__ Cout,
        __hip_bfloat16* __restrict__ Qbuf,
        __hip_bfloat16* __restrict__ Kbuf,
        __hip_bfloat16* __restrict__ Vtbuf,
        int M, int N, int K)
{
  __shared__ short As[128*64];   // 16 KB, 8 chunks(16B) per row
  __shared__ short Bs[128*64];   // 16 KB
  const int mb = blockIdx.y, nb = blockIdx.x;
  const int tid  = threadIdx.x;
  const int wave = tid >> 6, lane = tid & 63;
  const int wm = wave >> 1, wn = wave & 1;
  const int quad = lane >> 4, l15 = lane & 15;

  floatx4 acc[4][4] = {};

  const __hip_bfloat16* Abase = A  + (size_t)mb * 128 * K;
  const __hip_bfloat16* Bbase = Bm + (size_t)nb * 128 * K;

  for (int kb = 0; kb < K; kb += 64) {
    #pragma unroll
    for (int i = 0; i < 4; ++i) {
      const int cb  = (i*4 + wave) * 64;     // wave-uniform chunk base
      const int idx = cb + lane;
      const int r   = idx >> 3, cl = idx & 7;
      const int gc  = cl ^ (r & 7);          // XOR swizzle (global side)
      async_ld16(Abase + (size_t)r*K + kb + gc*8, As + cb*8);
      async_ld16(Bbase + (size_t)r*K + kb + gc*8, Bs + cb*8);
    }
    __syncthreads();

    #pragma unroll
    for (int ks = 0; ks < 2; ++ks) {
      short8 af[4], bf[4];
      #pragma unroll
      for (int mi = 0; mi < 4; ++mi) {
        const int row = wm*64 + mi*16 + l15;
        const int ch  = (ks*4 + quad) ^ (l15 & 7);
        af[mi] = *(const short8*)&As[row*64 + ch*8];
      }
      #pragma unroll
      for (int ni = 0; ni < 4; ++ni) {
        const int row = wn*64 + ni*16 + l15;
        const int ch  = (ks*4 + quad) ^ (l15 & 7);
        bf[ni] = *(const short8*)&Bs[row*64 + ch*8];
      }
      #pragma unroll
      for (int mi = 0; mi < 4; ++mi)
        #pragma unroll
        for (int ni = 0; ni < 4; ++ni)
          acc[mi][ni] = __builtin_amdgcn_mfma_f32_16x16x32_bf16(
              af[mi], bf[ni], acc[mi][ni], 0, 0, 0);
    }
    __syncthreads();
  }

  // epilogue: C/D layout col = lane&15, row = quad*4 + reg
  #pragma unroll
  for (int mi = 0; mi < 4; ++mi) {
    #pragma unroll
    for (int ni = 0; ni < 4; ++ni) {
      const int n = nb*128 + wn*64 + ni*16 + l15;
      float bv = 0.0f;
      if (MODE == 1) bv = bias[n];
      #pragma unroll
      for (int r = 0; r < 4; ++r) {
        const int m = mb*128 + wm*64 + mi*16 + quad*4 + r;
        float v = acc[mi][ni][r] + bv;
        if (MODE == 0) {
          Cout[(size_t)m*N + n] = v;
        } else {
          const int s  = m >> 1;       // BATCH = 2
          const int bi = m & 1;
          // fused RoPE for Q and K regions (n < 5120; boundary is 16-aligned
          // so the branch is uniform across each 16-lane n-span; all 64
          // lanes reach the shfl together since n doesn't depend on quad)
          if (n < HDIM + NGROUPS*HEADD) {
            const int d = n & 127;
            const float2 cs = *(const float2*)&rope[s*128 + (d & ~1)];
            const float vp = __shfl_xor(v, 1);
            // even d=2i: x0*c - x1*sn ; odd d=2i+1: x1*c + x0*sn
            float o = v*cs.x + ((d & 1) ? vp : -vp)*cs.y;
            if (n < HDIM) o *= 0.12751744061558475f;  // Q: 1/sqrt(128)*log2e
            v = o;
          }
          const __hip_bfloat16 hv = __float2bfloat16(v);
          if (n < HDIM) {                     // Q -> (b,h,s,d)
            const int hh = n >> 7, d = n & 127;
            Qbuf[(((size_t)bi*NHEADS + hh)*S_LEN + s)*HEADD + d] = hv;
          } else if (n < HDIM + NGROUPS*HEADD) {  // K -> (b,g,s,d)
            const int gg = (n - HDIM) >> 7, d = n & 127;
            Kbuf[(((size_t)bi*NGROUPS + gg)*S_LEN + s)*HEADD + d] = hv;
          } else {                            // V -> (b,g,d,s) transposed
            const int gg = (n - (HDIM + NGROUPS*HEADD)) >> 7, d = n & 127;
            Vtbuf[(((size_t)bi*NGROUPS + gg)*HEADD + d)*S_LEN + s] = hv;
          }
        }
      }
    }
  }
}

// ---------------------------------------------------------------------------
// Flash attention v3 (verified 164 us): causal, GQA rep=4.
// Block = 4 waves x 16 q-rows; K/V tiles (64 keys) staged via XOR-swizzled
// DMA (conflict-free fragment reads). No-max softmax (Q pre-scaled into
// exp2 domain by the fused-RoPE GEMM epilogue). Mask only on the diagonal
// iteration. 2 barriers/iter; 12 waves/CU of cross-block overlap hides the
// serial chain (rounds 1/2/4 proved: do not change this structure).
// ---------------------------------------------------------------------------
__global__ void __launch_bounds__(256)
attn_kernel(const __hip_bfloat16* __restrict__ Qbuf,
            const __hip_bfloat16* __restrict__ Kbuf,
            const __hip_bfloat16* __restrict__ Vtbuf,
            __hip_bfloat16* __restrict__ Obuf)
{
  __shared__ __align__(16) short KtS[64*128];    // 16 KB: [key][d], 16 ch/row
  __shared__ __align__(16) short VtS[128*64];    // 16 KB: [d][key], 8 ch/row
  __shared__ __align__(16) short PtS[4][16*72];  // 9 KB: per-wave P, pad 64->72

  const int qb   = blockIdx.x * 64;
  const int bh   = blockIdx.y;               // b*NHEADS + h
  const int b    = bh >> 5, h = bh & 31;
  const int g    = h >> 2;                   // rep = 4
  const int tid  = threadIdx.x;
  const int wave = tid >> 6, lane = tid & 63;
  const int quad = lane >> 4, l15 = lane & 15;
  const int qw   = qb + wave*16;             // this wave's q rows

  const __hip_bfloat16* Qp = Qbuf  + ((size_t)bh*S_LEN + qw) * HEADD;
  const __hip_bfloat16* Kp = Kbuf  + ((size_t)(b*NGROUPS + g)*S_LEN) * HEADD;
  const __hip_bfloat16* Vp = Vtbuf + ((size_t)(b*NGROUPS + g)*HEADD) * S_LEN;

  // Q fragments (already scaled by 1/sqrt(d)*log2e in the GEMM epilogue)
  short8 aq[4];
  #pragma unroll
  for (int dc = 0; dc < 4; ++dc)
    aq[dc] = *(const short8*)&Qp[(size_t)l15*HEADD + dc*32 + quad*8];

  floatx4 O[8] = {};
  float li[4] = {0.f, 0.f, 0.f, 0.f};   // per-lane partial row sums

  const int ktend = qb + 64;
  for (int kt = 0; kt < ktend; kt += 64) {
    // ---- stage K (64x128) and V^T (128x64) tiles, XOR-swizzled ----
    #pragma unroll
    for (int i = 0; i < 4; ++i) {
      const int cb  = (i*4 + wave) * 64;     // wave-uniform chunk base
      const int idx = cb + lane;
      { // K: 16 chunks per key row; chunk (r,cl) holds global chunk cl^(r&15)
        const int r = idx >> 4, cl = idx & 15;
        const int gc = cl ^ (r & 15);
        async_ld16(Kp + (size_t)(kt + r)*HEADD + gc*8, KtS + cb*8);
      }
      { // V: 8 chunks per d row; chunk (r,cl) holds global chunk cl^(r&7)
        const int r = idx >> 3, cl = idx & 7;
        const int gc = cl ^ (r & 7);
        async_ld16(Vp + (size_t)r*S_LEN + kt + gc*8, VtS + cb*8);
      }
    }
    __syncthreads();   // barrier drains vmcnt(0): tiles ready

    // ---- S = Q K^T : 16 rows x 64 keys, 16 MFMAs ----
    floatx4 s[4] = {};
    __builtin_amdgcn_s_setprio(1);
    #pragma unroll
    for (int dc = 0; dc < 4; ++dc) {
      #pragma unroll
      for (int kc = 0; kc < 4; ++kc) {
        const int row = kc*16 + l15;
        const int ch  = (dc*4 + quad) ^ l15;
        const short8 bk = *(const short8*)&KtS[row*128 + ch*8];
        s[kc] = __builtin_amdgcn_mfma_f32_16x16x32_bf16(aq[dc], bk, s[kc], 0, 0, 0);
      }
    }
    __builtin_amdgcn_s_setprio(0);

    // ---- no-max softmax: p = exp2(s); mask only on diagonal iteration ----
    if (kt == qb) {
      #pragma unroll
      for (int r = 0; r < 4; ++r) {
        const int row = qw + quad*4 + r;
        float rs = 0.f;
        #pragma unroll
        for (int kc = 0; kc < 4; ++kc) {
          const int col = kt + kc*16 + l15;
          const float p = (col > row) ? 0.0f : __builtin_amdgcn_exp2f(s[kc][r]);
          s[kc][r] = p; rs += p;
        }
        li[r] += rs;
      }
    } else {
      #pragma unroll
      for (int r = 0; r < 4; ++r) {
        float rs = 0.f;
        #pragma unroll
        for (int kc = 0; kc < 4; ++kc) {
          const float p = __builtin_amdgcn_exp2f(s[kc][r]);
          s[kc][r] = p; rs += p;
        }
        li[r] += rs;
      }
    }

    // ---- P: C-layout -> A-layout via wave-private padded LDS tile ----
    #pragma unroll
    for (int r = 0; r < 4; ++r)
      #pragma unroll
      for (int kc = 0; kc < 4; ++kc)
        PtS[wave][(quad*4 + r)*72 + kc*16 + l15] = (short)f2bf_bits(s[kc][r]);
    // same-wave RAW through LDS: ordered by lgkmcnt, no block barrier needed
    const short8 pa0 = *(const short8*)&PtS[wave][l15*72 +      quad*8];
    const short8 pa1 = *(const short8*)&PtS[wave][l15*72 + 32 + quad*8];

    // ---- O += P V : 16 MFMAs ----
    __builtin_amdgcn_s_setprio(1);
    #pragma unroll
    for (int dt = 0; dt < 8; ++dt) {
      const int row = dt*16 + l15;
      const int c0 = quad ^ (l15 & 7);
      const int c1 = (4 + quad) ^ (l15 & 7);
      const short8 bv0 = *(const short8*)&VtS[row*64 + c0*8];
      const short8 bv1 = *(const short8*)&VtS[row*64 + c1*8];
      O[dt] = __builtin_amdgcn_mfma_f32_16x16x32_bf16(pa0, bv0, O[dt], 0, 0, 0);
      O[dt] = __builtin_amdgcn_mfma_f32_16x16x32_bf16(pa1, bv1, O[dt], 0, 0, 0);
    }
    __builtin_amdgcn_s_setprio(0);

    __syncthreads();   // all tile reads done before next stage overwrites
  }

  // ---- epilogue: reduce l across the 16 col-lanes, scale, write ----
  float inv[4];
  #pragma unroll
  for (int r = 0; r < 4; ++r) {
    float l = li[r];
    l += __shfl_xor(l, 1, 16);
    l += __shfl_xor(l, 2, 16);
    l += __shfl_xor(l, 4, 16);
    l += __shfl_xor(l, 8, 16);
    inv[r] = 1.0f / l;
  }
  #pragma unroll
  for (int dt = 0; dt < 8; ++dt)
    #pragma unroll
    for (int r = 0; r < 4; ++r) {
      const int row = qw + quad*4 + r;
      Obuf[((size_t)row*BATCH + b)*HDIM + h*HEADD + dt*16 + l15] =
          __float2bfloat16(O[dt][r] * inv[r]);
    }
}

// ---------------------------------------------------------------------------
extern "C" void kernel_launch(void* const* d_in, const int* in_sizes, int n_in,
                              void* d_out, int out_size, void* d_ws, size_t ws_size,
                              hipStream_t stream)
{
  const float* x    = (const float*)d_in[0];
  const float* rope = (const float*)d_in[1];
  const float* Wqkv = (const float*)d_in[2];
  const float* bqkv = (const float*)d_in[3];
  const float* Wd   = (const float*)d_in[4];
  float* out = (float*)d_out;

  const size_t MiB = 1024*1024;
  char* ws = (char*)d_ws;
  __hip_bfloat16* xb    = (__hip_bfloat16*)(ws);              // 32 MiB
  __hip_bfloat16* Wqkvb = (__hip_bfloat16*)(ws + 32*MiB);     // 48 MiB
  __hip_bfloat16* Wdb   = (__hip_bfloat16*)(ws + 80*MiB);     // 32 MiB
  __hip_bfloat16* Qbuf  = (__hip_bfloat16*)(ws + 112*MiB);    // 32 MiB
  __hip_bfloat16* Kbuf  = (__hip_bfloat16*)(ws + 144*MiB);    //  8 MiB
  __hip_bfloat16* Vt    = (__hip_bfloat16*)(ws + 152*MiB);    //  8 MiB
  __hip_bfloat16* Ob    = (__hip_bfloat16*)(ws + 160*MiB);    // 32 MiB

  // 0) f32 -> bf16 conversions (single fused launch)
  {
    const int nx = S_LEN*BATCH*HDIM/4;
    const int nq = QKV_N*HDIM/4;
    const int nd = HDIM*HDIM/4;
    const int nt = nx + nq + nd;
    cvt_all<<<(nt+255)/256, 256, 0, stream>>>(
        (const float4*)x, (const float4*)Wqkv, (const float4*)Wd,
        (ushort4*)xb, (ushort4*)Wqkvb, (ushort4*)Wdb, nx, nq, nd);
  }

  // 1) QKV projection + scatter + fused RoPE (M=4096, N=6144, K=4096)
  dim3 g1(QKV_N/128, (S_LEN*BATCH)/128);
  gemm128<1><<<g1, 256, 0, stream>>>(xb, Wqkvb, bqkv, rope,
                                     nullptr, Qbuf, Kbuf, Vt,
                                     S_LEN*BATCH, QKV_N, HDIM);

  // 2) causal flash attention (64 q-rows per block, 4 waves)
  dim3 ga(S_LEN/64, BATCH*NHEADS);
  attn_kernel<<<ga, 256, 0, stream>>>(Qbuf, Kbuf, Vt, Ob);

  // 3) dense projection (M=4096, N=4096, K=4096), f32 out
  dim3 g2(HDIM/128, (S_LEN*BATCH)/128);
  gemm128<0><<<g2, 256, 0, stream>>>(Ob, Wdb, nullptr, nullptr,
                                     out, nullptr, nullptr, nullptr,
                                     S_LEN*BATCH, HDIM, HDIM);
}